// Round 4
// baseline (40.786 us; speedup 1.0000x reference)
//
#include <hip/hip_runtime.h>
#include <math.h>

// Banded self-attention, fp32. B=4, T=4096, D=64, MASK_NUM=64.
// One 64-lane wave handles FOUR consecutive query rows (t0..t0+3): their
// bands overlap in all but 3 keys, so each K/V row load feeds four dots.
// 8 subgroups of 8 lanes; subgroup g handles key slots s = s_lo+g+8i.
// Lane r of a subgroup owns dims [8r, 8r+8).
// Whole-band scores live in registers (p[4][18]) -> batched softmax.
// In-subgroup dot reduction uses DPP adds (pure VALU, no LDS pipe).
// K/V loads are issued in batches of 6 rows for memory-level parallelism.

constexpr int kB = 4;
constexpr int kT = 4096;
constexpr int kD = 64;
constexpr int kBand = 64;   // MASK_NUM
constexpr int kQ = 4;       // queries per wave
constexpr int kIters = 18;  // covers the 131+3-key window, kBatch multiple
constexpr int kBatch = 6;

__device__ __forceinline__ float sum8_dpp(float x) {
    // all-lanes sum within each 8-lane group:
    // quad_perm xor1 (0xB1), quad_perm xor2 (0x4E), row_half_mirror (0x141)
    int v = __float_as_int(x);
    x += __int_as_float(__builtin_amdgcn_update_dpp(0, v, 0xB1, 0xF, 0xF, true));
    v = __float_as_int(x);
    x += __int_as_float(__builtin_amdgcn_update_dpp(0, v, 0x4E, 0xF, 0xF, true));
    v = __float_as_int(x);
    x += __int_as_float(__builtin_amdgcn_update_dpp(0, v, 0x141, 0xF, 0xF, true));
    return x;
}

__global__ __launch_bounds__(256, 2) void band_attn_kernel(
    const float* __restrict__ Q,
    const float* __restrict__ K,
    const float* __restrict__ V,
    const int*   __restrict__ M,
    float* __restrict__ O)
{
    const int lane = threadIdx.x & 63;
    const int wid  = threadIdx.x >> 6;
    const int gw   = (blockIdx.x << 2) + wid;      // global wave id
    if (gw >= (kB * kT) / kQ) return;
    const int b  = gw >> 10;                       // 1024 waves per batch
    const int t0 = (gw & 1023) << 2;               // first of 4 queries
    const int row0 = b * kT + t0;

    const int g = lane >> 3;   // subgroup 0..7 (key slot)
    const int r = lane & 7;    // dims 8r..8r+7

    // load + pre-scale the four query rows (each lane: dims 8r..8r+7)
    float4 q[kQ][2];
    #pragma unroll
    for (int j = 0; j < kQ; ++j) {
        const float* qr = Q + (size_t)(row0 + j) * kD + 8 * r;
        q[j][0] = *reinterpret_cast<const float4*>(qr);
        q[j][1] = *reinterpret_cast<const float4*>(qr + 4);
        q[j][0].x *= 0.125f; q[j][0].y *= 0.125f; q[j][0].z *= 0.125f; q[j][0].w *= 0.125f;
        q[j][1].x *= 0.125f; q[j][1].y *= 0.125f; q[j][1].z *= 0.125f; q[j][1].w *= 0.125f;
    }

    const float* kb = K + (size_t)b * kT * kD;
    const float* vb = V + (size_t)b * kT * kD;
    const int*   mb = M + b * kT;

    const bool allq = mb[t0] && mb[t0 + 1] && mb[t0 + 2] && mb[t0 + 3];

    if (allq) {
        // -------- fast path: all four queries banded --------
        int s_lo = t0 - kBand;            if (s_lo < 0) s_lo = 0;
        int s_hi = t0 + (kQ - 1) + kBand; if (s_hi > kT - 1) s_hi = kT - 1;
        const int s0 = s_lo + g;

        // key-mask bits, one per slot
        unsigned mv = 0u;
        #pragma unroll
        for (int i = 0; i < kIters; ++i) {
            const int s  = s0 + 8 * i;
            const int sc = (s <= s_hi) ? s : s_hi;
            mv |= (mb[sc] ? 1u : 0u) << i;
        }

        // ---- phase 1: all scores into registers (batched K loads) ----
        float p[kQ][kIters];
        #pragma unroll
        for (int base = 0; base < kIters; base += kBatch) {
            float4 ka[kBatch], kc[kBatch];
            #pragma unroll
            for (int jj = 0; jj < kBatch; ++jj) {
                const int s  = s0 + 8 * (base + jj);
                const int sc = (s <= s_hi) ? s : s_hi;
                const float* kr = kb + (size_t)sc * kD + 8 * r;
                ka[jj] = *reinterpret_cast<const float4*>(kr);
                kc[jj] = *reinterpret_cast<const float4*>(kr + 4);
            }
            #pragma unroll
            for (int jj = 0; jj < kBatch; ++jj) {
                const int i = base + jj;
                const int s = s0 + 8 * i;
                const bool inr = (s <= s_hi);
                const bool mk  = (mv >> i) & 1u;
                #pragma unroll
                for (int j = 0; j < kQ; ++j) {
                    float d = q[j][0].x * ka[jj].x + q[j][0].y * ka[jj].y
                            + q[j][0].z * ka[jj].z + q[j][0].w * ka[jj].w
                            + q[j][1].x * kc[jj].x + q[j][1].y * kc[jj].y
                            + q[j][1].z * kc[jj].z + q[j][1].w * kc[jj].w;
                    d = sum8_dpp(d);
                    const int tj = t0 + j;
                    const bool band = (s >= tj - kBand) && (s <= tj + kBand);
                    p[j][i] = (inr && mk && band) ? d : -INFINITY;
                }
            }
        }

        // ---- phase 2: row maxima (batched) ----
        float mx[kQ];
        #pragma unroll
        for (int j = 0; j < kQ; ++j) {
            float m = p[j][0];
            #pragma unroll
            for (int i = 1; i < kIters; ++i) m = fmaxf(m, p[j][i]);
            mx[j] = m;
        }
        #pragma unroll
        for (int off = 8; off <= 32; off <<= 1) {
            #pragma unroll
            for (int j = 0; j < kQ; ++j)
                mx[j] = fmaxf(mx[j], __shfl_xor(mx[j], off, 64));
        }

        // ---- phase 3: exp + sum + PV (batched V loads) ----
        float  l[kQ] = {0.f, 0.f, 0.f, 0.f};
        float4 a[kQ][2];
        #pragma unroll
        for (int j = 0; j < kQ; ++j) {
            a[j][0] = make_float4(0.f, 0.f, 0.f, 0.f);
            a[j][1] = make_float4(0.f, 0.f, 0.f, 0.f);
        }
        #pragma unroll
        for (int base = 0; base < kIters; base += kBatch) {
            float4 va[kBatch], vc[kBatch];
            #pragma unroll
            for (int jj = 0; jj < kBatch; ++jj) {
                const int s  = s0 + 8 * (base + jj);
                const int sc = (s <= s_hi) ? s : s_hi;
                const float* vr = vb + (size_t)sc * kD + 8 * r;
                va[jj] = *reinterpret_cast<const float4*>(vr);
                vc[jj] = *reinterpret_cast<const float4*>(vr + 4);
            }
            #pragma unroll
            for (int jj = 0; jj < kBatch; ++jj) {
                const int i = base + jj;
                #pragma unroll
                for (int j = 0; j < kQ; ++j) {
                    const float w = __expf(p[j][i] - mx[j]);  // exp(-inf)=0
                    l[j] += w;
                    a[j][0].x += w * va[jj].x; a[j][0].y += w * va[jj].y;
                    a[j][0].z += w * va[jj].z; a[j][0].w += w * va[jj].w;
                    a[j][1].x += w * vc[jj].x; a[j][1].y += w * vc[jj].y;
                    a[j][1].z += w * vc[jj].z; a[j][1].w += w * vc[jj].w;
                }
            }
        }

        // ---- merge the 8 subgroup partials (butterfly: all lanes get totals) ----
        #pragma unroll
        for (int off = 8; off <= 32; off <<= 1) {
            #pragma unroll
            for (int j = 0; j < kQ; ++j) {
                l[j] += __shfl_xor(l[j], off, 64);
                a[j][0].x += __shfl_xor(a[j][0].x, off, 64);
                a[j][0].y += __shfl_xor(a[j][0].y, off, 64);
                a[j][0].z += __shfl_xor(a[j][0].z, off, 64);
                a[j][0].w += __shfl_xor(a[j][0].w, off, 64);
                a[j][1].x += __shfl_xor(a[j][1].x, off, 64);
                a[j][1].y += __shfl_xor(a[j][1].y, off, 64);
                a[j][1].z += __shfl_xor(a[j][1].z, off, 64);
                a[j][1].w += __shfl_xor(a[j][1].w, off, 64);
            }
        }

        if (g < kQ) {
            const int j = g;
            const float inv = 1.0f / l[j];
            float* orow = O + (size_t)(row0 + j) * kD + 8 * r;
            float4 o0, o1;
            o0.x = a[j][0].x * inv; o0.y = a[j][0].y * inv;
            o0.z = a[j][0].z * inv; o0.w = a[j][0].w * inv;
            o1.x = a[j][1].x * inv; o1.y = a[j][1].y * inv;
            o1.z = a[j][1].z * inv; o1.w = a[j][1].w * inv;
            *reinterpret_cast<float4*>(orow)     = o0;
            *reinterpret_cast<float4*>(orow + 4) = o1;
        }
        return;
    }

    // -------- generic fallback (not hit by the bench mask): per query --------
    #pragma unroll 1
    for (int qq = 0; qq < kQ; ++qq) {
        const int t  = t0 + qq;
        const int qm = mb[t];
        const float4 q0 = q[qq][0];
        const float4 q1 = q[qq][1];
        int lo, hi;
        if (qm) {
            lo = t - kBand; if (lo < 0) lo = 0;
            hi = t + kBand; if (hi > kT - 1) hi = kT - 1;
        } else {
            lo = 0; hi = kT - 1;
        }
        float m = -INFINITY, l = 0.f;
        float4 acc0 = make_float4(0.f,0.f,0.f,0.f), acc1 = acc0;
        for (int s = lo + g; s <= hi; s += 8) {
            const float* kr = kb + (size_t)s * kD + 8 * r;
            const float4 k0 = *reinterpret_cast<const float4*>(kr);
            const float4 k1 = *reinterpret_cast<const float4*>(kr + 4);
            float d = q0.x * k0.x + q0.y * k0.y + q0.z * k0.z + q0.w * k0.w
                    + q1.x * k1.x + q1.y * k1.y + q1.z * k1.z + q1.w * k1.w;
            d = sum8_dpp(d);
            if (mb[s]) {
                const float mn  = fmaxf(m, d);
                const float scl = __expf(m - mn);
                const float w   = __expf(d - mn);
                const float* vr = vb + (size_t)s * kD + 8 * r;
                const float4 v0 = *reinterpret_cast<const float4*>(vr);
                const float4 v1 = *reinterpret_cast<const float4*>(vr + 4);
                l = l * scl + w;
                acc0.x = acc0.x * scl + w * v0.x; acc0.y = acc0.y * scl + w * v0.y;
                acc0.z = acc0.z * scl + w * v0.z; acc0.w = acc0.w * scl + w * v0.w;
                acc1.x = acc1.x * scl + w * v1.x; acc1.y = acc1.y * scl + w * v1.y;
                acc1.z = acc1.z * scl + w * v1.z; acc1.w = acc1.w * scl + w * v1.w;
                m = mn;
            }
        }
        #pragma unroll
        for (int off = 8; off <= 32; off <<= 1) {
            const float m2 = __shfl_xor(m, off, 64);
            const float l2 = __shfl_xor(l, off, 64);
            float4 b0, b1;
            b0.x = __shfl_xor(acc0.x, off, 64); b0.y = __shfl_xor(acc0.y, off, 64);
            b0.z = __shfl_xor(acc0.z, off, 64); b0.w = __shfl_xor(acc0.w, off, 64);
            b1.x = __shfl_xor(acc1.x, off, 64); b1.y = __shfl_xor(acc1.y, off, 64);
            b1.z = __shfl_xor(acc1.z, off, 64); b1.w = __shfl_xor(acc1.w, off, 64);
            const float mm = fmaxf(m, m2);
            const float e1 = (m  == -INFINITY) ? 0.f : __expf(m  - mm);
            const float e2 = (m2 == -INFINITY) ? 0.f : __expf(m2 - mm);
            l = l * e1 + l2 * e2;
            acc0.x = acc0.x * e1 + b0.x * e2; acc0.y = acc0.y * e1 + b0.y * e2;
            acc0.z = acc0.z * e1 + b0.z * e2; acc0.w = acc0.w * e1 + b0.w * e2;
            acc1.x = acc1.x * e1 + b1.x * e2; acc1.y = acc1.y * e1 + b1.y * e2;
            acc1.z = acc1.z * e1 + b1.z * e2; acc1.w = acc1.w * e1 + b1.w * e2;
            m = mm;
        }
        if (g == 0) {
            const float inv = 1.0f / l;
            float* orow = O + (size_t)(b * kT + t) * kD + 8 * r;
            float4 o0, o1;
            o0.x = acc0.x * inv; o0.y = acc0.y * inv;
            o0.z = acc0.z * inv; o0.w = acc0.w * inv;
            o1.x = acc1.x * inv; o1.y = acc1.y * inv;
            o1.z = acc1.z * inv; o1.w = acc1.w * inv;
            *reinterpret_cast<float4*>(orow)     = o0;
            *reinterpret_cast<float4*>(orow + 4) = o1;
        }
    }
}

extern "C" void kernel_launch(void* const* d_in, const int* in_sizes, int n_in,
                              void* d_out, int out_size, void* d_ws, size_t ws_size,
                              hipStream_t stream) {
    const float* q    = (const float*)d_in[0];
    const float* k    = (const float*)d_in[1];
    const float* v    = (const float*)d_in[2];
    const int*   mask = (const int*)d_in[3];
    float*       out  = (float*)d_out;

    const int waves = (kB * kT) / kQ;         // 4096 waves
    dim3 grid(waves / 4);                     // 4 waves per block
    dim3 block(256);
    band_attn_kernel<<<grid, block, 0, stream>>>(q, k, v, mask, out);
}

// Round 5
// 31.984 us; speedup vs baseline: 1.2752x; 1.2752x over previous
//
#include <hip/hip_runtime.h>
#include <math.h>

// Banded self-attention, fp32. B=4, T=4096, D=64, MASK_NUM=64.
// One 64-lane wave handles FOUR consecutive query rows (t0..t0+3); each K/V
// row load feeds four dots. 8 subgroups of 8 lanes; subgroup g handles key
// slots s = s_lo+g+8i. Lane r of a subgroup owns dims [8r, 8r+8).
// SINGLE fused pass with deferred-max online softmax: no score array, no
// separate max pass -> tiny register state, no spills (round-4 lesson:
// p[4][18] + batch buffers spilled to scratch, 65 MB of scratch writes).
// The rescale branch fires ~3x per lane total on real data.
// K/V loads run one slot ahead in a 2-buffer software pipeline.
// NOTE: every local array is indexed ONLY by compile-time constants
// (unrolled loops / macro output writes) so nothing lands in scratch.

constexpr int kB = 4;
constexpr int kT = 4096;
constexpr int kD = 64;
constexpr int kBand = 64;   // MASK_NUM
constexpr int kQ = 4;       // queries per wave
constexpr int kIters = 17;  // ceil((2*kBand + kQ)/8) = ceil(132/8)

__device__ __forceinline__ float sum8_dpp(float x) {
    // all-lanes sum within each 8-lane group:
    // quad_perm xor1 (0xB1), quad_perm xor2 (0x4E), row_half_mirror (0x141)
    int v = __float_as_int(x);
    x += __int_as_float(__builtin_amdgcn_update_dpp(0, v, 0xB1, 0xF, 0xF, true));
    v = __float_as_int(x);
    x += __int_as_float(__builtin_amdgcn_update_dpp(0, v, 0x4E, 0xF, 0xF, true));
    v = __float_as_int(x);
    x += __int_as_float(__builtin_amdgcn_update_dpp(0, v, 0x141, 0xF, 0xF, true));
    return x;
}

__global__ __launch_bounds__(256, 2) void band_attn_kernel(
    const float* __restrict__ Q,
    const float* __restrict__ K,
    const float* __restrict__ V,
    const int*   __restrict__ M,
    float* __restrict__ O)
{
    const int lane = threadIdx.x & 63;
    const int wid  = threadIdx.x >> 6;
    const int gw   = (blockIdx.x << 2) + wid;      // global wave id
    if (gw >= (kB * kT) / kQ) return;
    const int b  = gw >> 10;                       // 1024 waves per batch
    const int t0 = (gw & 1023) << 2;               // first of 4 queries
    const int row0 = b * kT + t0;

    const int g = lane >> 3;   // subgroup 0..7 (key slot)
    const int r = lane & 7;    // dims 8r..8r+7

    // load + pre-scale the four query rows (each lane: dims 8r..8r+7)
    float4 q[kQ][2];
    #pragma unroll
    for (int j = 0; j < kQ; ++j) {
        const float* qr = Q + (size_t)(row0 + j) * kD + 8 * r;
        q[j][0] = *reinterpret_cast<const float4*>(qr);
        q[j][1] = *reinterpret_cast<const float4*>(qr + 4);
        q[j][0].x *= 0.125f; q[j][0].y *= 0.125f; q[j][0].z *= 0.125f; q[j][0].w *= 0.125f;
        q[j][1].x *= 0.125f; q[j][1].y *= 0.125f; q[j][1].z *= 0.125f; q[j][1].w *= 0.125f;
    }

    const float* kb = K + (size_t)b * kT * kD;
    const float* vb = V + (size_t)b * kT * kD;
    const int*   mb = M + b * kT;

    const bool allq = mb[t0] && mb[t0 + 1] && mb[t0 + 2] && mb[t0 + 3];

    if (allq) {
        // -------- fast path: all four queries banded --------
        int s_lo = t0 - kBand;            if (s_lo < 0) s_lo = 0;
        int s_hi = t0 + (kQ - 1) + kBand; if (s_hi > kT - 1) s_hi = kT - 1;
        const int s0 = s_lo + g;

        // key-mask bits, one per slot
        unsigned mv = 0u;
        #pragma unroll
        for (int i = 0; i < kIters; ++i) {
            const int s  = s0 + 8 * i;
            const int sc = (s <= s_hi) ? s : s_hi;
            mv |= (mb[sc] ? 1u : 0u) << i;
        }

        // online-softmax state (all statically indexed)
        float  m_[kQ] = {-INFINITY, -INFINITY, -INFINITY, -INFINITY};
        float  l_[kQ] = {0.f, 0.f, 0.f, 0.f};
        float4 a_[kQ][2];
        #pragma unroll
        for (int j = 0; j < kQ; ++j) {
            a_[j][0] = make_float4(0.f, 0.f, 0.f, 0.f);
            a_[j][1] = make_float4(0.f, 0.f, 0.f, 0.f);
        }

        auto loadKV = [&](int i, float4& ka, float4& kc, float4& va, float4& vc) {
            const int s  = s0 + 8 * i;
            const int sc = (s <= s_hi) ? s : s_hi;
            const float* kr = kb + (size_t)sc * kD + 8 * r;
            const float* vr = vb + (size_t)sc * kD + 8 * r;
            ka = *reinterpret_cast<const float4*>(kr);
            kc = *reinterpret_cast<const float4*>(kr + 4);
            va = *reinterpret_cast<const float4*>(vr);
            vc = *reinterpret_cast<const float4*>(vr + 4);
        };

        auto compute = [&](int i, const float4& ka, const float4& kc,
                           const float4& va, const float4& vc) {
            const int s   = s0 + 8 * i;
            const bool inr = (s <= s_hi);
            const bool mk  = (mv >> i) & 1u;
            const int  e   = s - t0;
            #pragma unroll
            for (int j = 0; j < kQ; ++j) {
                float d = q[j][0].x * ka.x + q[j][0].y * ka.y
                        + q[j][0].z * ka.z + q[j][0].w * ka.w
                        + q[j][1].x * kc.x + q[j][1].y * kc.y
                        + q[j][1].z * kc.z + q[j][1].w * kc.w;
                d = sum8_dpp(d);
                // band check: e - (j - kBand) in [0, 2*kBand]
                const bool valid = inr && mk &&
                    ((unsigned)(e - (j - kBand)) <= (unsigned)(2 * kBand));
                if (valid && d > m_[j]) {          // rare (deferred max)
                    const float scl = __expf(m_[j] - d);   // 0 on first hit
                    l_[j] *= scl;
                    a_[j][0].x *= scl; a_[j][0].y *= scl;
                    a_[j][0].z *= scl; a_[j][0].w *= scl;
                    a_[j][1].x *= scl; a_[j][1].y *= scl;
                    a_[j][1].z *= scl; a_[j][1].w *= scl;
                    m_[j] = d;
                }
                const float w = valid ? __expf(d - m_[j]) : 0.f;
                l_[j] += w;
                a_[j][0].x += w * va.x; a_[j][0].y += w * va.y;
                a_[j][0].z += w * va.z; a_[j][0].w += w * va.w;
                a_[j][1].x += w * vc.x; a_[j][1].y += w * vc.y;
                a_[j][1].z += w * vc.z; a_[j][1].w += w * vc.w;
            }
        };

        // 2-buffer software pipeline, one slot of prefetch
        float4 kA0, kC0, vA0, vC0, kA1, kC1, vA1, vC1;
        loadKV(0, kA0, kC0, vA0, vC0);
        #pragma unroll
        for (int i = 0; i < kIters; i += 2) {
            if (i + 1 < kIters) loadKV(i + 1, kA1, kC1, vA1, vC1);
            compute(i, kA0, kC0, vA0, vC0);
            if (i + 2 < kIters) loadKV(i + 2, kA0, kC0, vA0, vC0);
            if (i + 1 < kIters) compute(i + 1, kA1, kC1, vA1, vC1);
        }

        // ---- merge the 8 subgroup states ----
        // 1) global max per query, 2) rescale local state once, 3) plain sum
        #pragma unroll
        for (int j = 0; j < kQ; ++j) {
            float Mx = m_[j];
            Mx = fmaxf(Mx, __shfl_xor(Mx, 8, 64));
            Mx = fmaxf(Mx, __shfl_xor(Mx, 16, 64));
            Mx = fmaxf(Mx, __shfl_xor(Mx, 32, 64));
            const float scl = __expf(m_[j] - Mx);   // exp(-inf)=0 if empty
            l_[j] *= scl;
            a_[j][0].x *= scl; a_[j][0].y *= scl;
            a_[j][0].z *= scl; a_[j][0].w *= scl;
            a_[j][1].x *= scl; a_[j][1].y *= scl;
            a_[j][1].z *= scl; a_[j][1].w *= scl;
        }
        #pragma unroll
        for (int off = 8; off <= 32; off <<= 1) {
            #pragma unroll
            for (int j = 0; j < kQ; ++j) {
                l_[j] += __shfl_xor(l_[j], off, 64);
                a_[j][0].x += __shfl_xor(a_[j][0].x, off, 64);
                a_[j][0].y += __shfl_xor(a_[j][0].y, off, 64);
                a_[j][0].z += __shfl_xor(a_[j][0].z, off, 64);
                a_[j][0].w += __shfl_xor(a_[j][0].w, off, 64);
                a_[j][1].x += __shfl_xor(a_[j][1].x, off, 64);
                a_[j][1].y += __shfl_xor(a_[j][1].y, off, 64);
                a_[j][1].z += __shfl_xor(a_[j][1].z, off, 64);
                a_[j][1].w += __shfl_xor(a_[j][1].w, off, 64);
            }
        }

        // output: subgroup J writes query J (compile-time indices only)
        #define WRITE_OUT(J)                                                  \
            if (g == (J)) {                                                   \
                const float inv = 1.0f / l_[(J)];                             \
                float* orow = O + (size_t)(row0 + (J)) * kD + 8 * r;          \
                float4 o0, o1;                                                \
                o0.x = a_[(J)][0].x * inv; o0.y = a_[(J)][0].y * inv;         \
                o0.z = a_[(J)][0].z * inv; o0.w = a_[(J)][0].w * inv;         \
                o1.x = a_[(J)][1].x * inv; o1.y = a_[(J)][1].y * inv;         \
                o1.z = a_[(J)][1].z * inv; o1.w = a_[(J)][1].w * inv;         \
                *reinterpret_cast<float4*>(orow)     = o0;                    \
                *reinterpret_cast<float4*>(orow + 4) = o1;                    \
            }
        WRITE_OUT(0)
        WRITE_OUT(1)
        WRITE_OUT(2)
        WRITE_OUT(3)
        #undef WRITE_OUT
        return;
    }

    // -------- generic fallback (not hit by the bench mask) --------
    // fully unrolled so q[qq] stays statically indexed (no scratch)
    #pragma unroll
    for (int qq = 0; qq < kQ; ++qq) {
        const int t  = t0 + qq;
        const int qm = mb[t];
        const float4 q0 = q[qq][0];
        const float4 q1 = q[qq][1];
        int lo, hi;
        if (qm) {
            lo = t - kBand; if (lo < 0) lo = 0;
            hi = t + kBand; if (hi > kT - 1) hi = kT - 1;
        } else {
            lo = 0; hi = kT - 1;
        }
        float m = -INFINITY, l = 0.f;
        float4 acc0 = make_float4(0.f,0.f,0.f,0.f), acc1 = acc0;
        for (int s = lo + g; s <= hi; s += 8) {
            const float* kr = kb + (size_t)s * kD + 8 * r;
            const float4 k0 = *reinterpret_cast<const float4*>(kr);
            const float4 k1 = *reinterpret_cast<const float4*>(kr + 4);
            float d = q0.x * k0.x + q0.y * k0.y + q0.z * k0.z + q0.w * k0.w
                    + q1.x * k1.x + q1.y * k1.y + q1.z * k1.z + q1.w * k1.w;
            d = sum8_dpp(d);
            if (mb[s]) {
                if (d > m) {
                    const float scl = __expf(m - d);
                    l *= scl;
                    acc0.x *= scl; acc0.y *= scl; acc0.z *= scl; acc0.w *= scl;
                    acc1.x *= scl; acc1.y *= scl; acc1.z *= scl; acc1.w *= scl;
                    m = d;
                }
                const float w = __expf(d - m);
                const float* vr = vb + (size_t)s * kD + 8 * r;
                const float4 v0 = *reinterpret_cast<const float4*>(vr);
                const float4 v1 = *reinterpret_cast<const float4*>(vr + 4);
                l += w;
                acc0.x += w * v0.x; acc0.y += w * v0.y;
                acc0.z += w * v0.z; acc0.w += w * v0.w;
                acc1.x += w * v1.x; acc1.y += w * v1.y;
                acc1.z += w * v1.z; acc1.w += w * v1.w;
            }
        }
        // merge: max, rescale once, sum
        float Mx = m;
        Mx = fmaxf(Mx, __shfl_xor(Mx, 8, 64));
        Mx = fmaxf(Mx, __shfl_xor(Mx, 16, 64));
        Mx = fmaxf(Mx, __shfl_xor(Mx, 32, 64));
        const float scl = __expf(m - Mx);
        l *= scl;
        acc0.x *= scl; acc0.y *= scl; acc0.z *= scl; acc0.w *= scl;
        acc1.x *= scl; acc1.y *= scl; acc1.z *= scl; acc1.w *= scl;
        #pragma unroll
        for (int off = 8; off <= 32; off <<= 1) {
            l += __shfl_xor(l, off, 64);
            acc0.x += __shfl_xor(acc0.x, off, 64);
            acc0.y += __shfl_xor(acc0.y, off, 64);
            acc0.z += __shfl_xor(acc0.z, off, 64);
            acc0.w += __shfl_xor(acc0.w, off, 64);
            acc1.x += __shfl_xor(acc1.x, off, 64);
            acc1.y += __shfl_xor(acc1.y, off, 64);
            acc1.z += __shfl_xor(acc1.z, off, 64);
            acc1.w += __shfl_xor(acc1.w, off, 64);
        }
        if (g == 0) {
            const float inv = 1.0f / l;
            float* orow = O + (size_t)(b * kT + t) * kD + 8 * r;
            float4 o0, o1;
            o0.x = acc0.x * inv; o0.y = acc0.y * inv;
            o0.z = acc0.z * inv; o0.w = acc0.w * inv;
            o1.x = acc1.x * inv; o1.y = acc1.y * inv;
            o1.z = acc1.z * inv; o1.w = acc1.w * inv;
            *reinterpret_cast<float4*>(orow)     = o0;
            *reinterpret_cast<float4*>(orow + 4) = o1;
        }
    }
}

extern "C" void kernel_launch(void* const* d_in, const int* in_sizes, int n_in,
                              void* d_out, int out_size, void* d_ws, size_t ws_size,
                              hipStream_t stream) {
    const float* q    = (const float*)d_in[0];
    const float* k    = (const float*)d_in[1];
    const float* v    = (const float*)d_in[2];
    const int*   mask = (const int*)d_in[3];
    float*       out  = (float*)d_out;

    const int waves = (kB * kT) / kQ;         // 4096 waves
    dim3 grid(waves / 4);                     // 4 waves per block -> 1024 blocks
    dim3 block(256);
    band_attn_kernel<<<grid, block, 0, stream>>>(q, k, v, mask, out);
}